// Round 1
// baseline (218.283 us; speedup 1.0000x reference)
//
#include <hip/hip_runtime.h>
#include <cstdint>

#define A_DIM 1024
#define B_DIM 64
#define H_DIM 512
#define L_TXT 1024
#define L_IMG 256

// ---------------- ws layout (float offsets) ----------------
// region A (scratch, reused):
//   P1 : 4 mats * 4 kq * 64 * 1024 = 1,048,576
//   P4 : (1024 + 256) * 1024       = 1,310,720  (max)
//   P5 : 2 mats * 4 kq * 64 * 1024 =   524,288
#define WS_DF_OFF   1310720u   // df/dfi/g3/g4 : 4*64*1024 = 262,144
#define WS_E_OFF    1572864u   // e (65536) + e_img (16384) = 81,920
#define WS_CTX_OFF  1654784u   // ctx_t (65536) + ctx_i (65536)
// total = 1,785,856 floats = ~7.2 MB

// d_out layout (floats): ctx_mm[0..65535], attn[65536..131071],
// attn_img[131072..147455], coverage[147456..212991], coverage_img[212992..229375]

__device__ __forceinline__ float ftanh(float x) {
  float xc = fminf(fmaxf(x, -10.f), 10.f);
  float t  = __expf(2.f * xc);
  return (t - 1.f) * __builtin_amdgcn_rcpf(t + 1.f);
}

// K1: partials of dec @ {W1,W2,W3,W4}. grid = 1024 waves (1 wave/block).
// wave = (m, a-tile of 16, k-quarter of 256). lane = batch row b.
__global__ void k1_gemm_dec(const float* __restrict__ h0, const float* __restrict__ h1,
                            const float* __restrict__ W1, const float* __restrict__ W2,
                            const float* __restrict__ W3, const float* __restrict__ W4,
                            float* __restrict__ P1) {
  int wid  = blockIdx.x;            // 0..1023
  int m    = wid >> 8;              // 0..3
  int at   = (wid >> 2) & 63;       // 0..63
  int kq   = wid & 3;               // 0..3
  int lane = threadIdx.x;           // 0..63 == b
  const float* W = (m == 0) ? W1 : (m == 1) ? W2 : (m == 2) ? W3 : W4;
  int a0 = at * 16;
  int k0 = kq * 256;
  // dec[b][k] = k<512 ? h0[b][k] : h1[b][k-512]; k-quarter stays in one half.
  const float* dsrc = (k0 < 512) ? (h0 + lane * H_DIM + k0)
                                 : (h1 + lane * H_DIM + (k0 - 512));
  float acc[16];
#pragma unroll
  for (int t = 0; t < 16; ++t) acc[t] = 0.f;

  for (int kc = 0; kc < 16; ++kc) {
    const float4* dp = reinterpret_cast<const float4*>(dsrc + kc * 16);
    float4 d0 = dp[0], d1 = dp[1], d2 = dp[2], d3 = dp[3];
    float dk[16] = {d0.x, d0.y, d0.z, d0.w, d1.x, d1.y, d1.z, d1.w,
                    d2.x, d2.y, d2.z, d2.w, d3.x, d3.y, d3.z, d3.w};
    const float* Wp = W + (size_t)(k0 + kc * 16) * A_DIM + a0;
#pragma unroll
    for (int j = 0; j < 16; ++j) {
#pragma unroll
      for (int t = 0; t < 16; ++t)
        acc[t] = fmaf(dk[j], Wp[(size_t)j * A_DIM + t], acc[t]);  // W uniform -> s_load
    }
  }
  float* outp = P1 + ((size_t)(m * 4 + kq) * 64 + lane) * A_DIM + a0;
  float4* o4 = reinterpret_cast<float4*>(outp);
  o4[0] = make_float4(acc[0], acc[1], acc[2], acc[3]);
  o4[1] = make_float4(acc[4], acc[5], acc[6], acc[7]);
  o4[2] = make_float4(acc[8], acc[9], acc[10], acc[11]);
  o4[3] = make_float4(acc[12], acc[13], acc[14], acc[15]);
}

// K1b: df_all[m][b][a] = sum_kq P1 + bias_m[a]
__global__ __launch_bounds__(256) void k1b_reduce(
    const float* __restrict__ P1,
    const float* __restrict__ b1, const float* __restrict__ b2,
    const float* __restrict__ b3, const float* __restrict__ b4,
    float* __restrict__ df_all) {
  int tid = blockIdx.x * 256 + threadIdx.x;  // 0..262143
  int a = tid & 1023;
  int b = (tid >> 10) & 63;
  int m = tid >> 16;
  const float* bias = (m == 0) ? b1 : (m == 1) ? b2 : (m == 2) ? b3 : b4;
  size_t base = ((size_t)(m * 4) * 64 + b) * 1024 + a;
  float s = P1[base] + P1[base + 65536] + P1[base + 2 * 65536] + P1[base + 3 * 65536];
  df_all[tid] = s + bias[a];
}

// K2: e[b,l] = sum_a v[a]*tanh(feat + df + cov*wc). One wave per row.
// waves 0..65535 = text rows, 65536..81919 = img rows.
__global__ __launch_bounds__(256) void k2_energy(
    const float* __restrict__ enc_features, const float* __restrict__ enc_img_features,
    const float* __restrict__ coverage, const float* __restrict__ coverage_img,
    const float* __restrict__ df_all,
    const float* __restrict__ v1, const float* __restrict__ v2,
    const float* __restrict__ wc, const float* __restrict__ wci,
    const int* __restrict__ cov_set_p,
    float* __restrict__ e_all) {
  int wg   = blockIdx.x * 4 + (threadIdx.x >> 6);
  int lane = threadIdx.x & 63;
  float covscale = (float)(*cov_set_p);
  const float *feat, *dfp, *vv, *wcp;
  float cov;
  if (wg < 65536) {
    int b = wg >> 10;
    feat = enc_features + (size_t)wg * 1024;
    dfp  = df_all + (size_t)b * 1024;            // df
    vv = v1; wcp = wc;
    cov = coverage[wg] * covscale;
  } else {
    int wg2 = wg - 65536;
    int b = wg2 >> 8;
    feat = enc_img_features + (size_t)wg2 * 1024;
    dfp  = df_all + 65536 + (size_t)b * 1024;    // dfi
    vv = v2; wcp = wci;
    cov = coverage_img[wg2] * covscale;
  }
  float acc = 0.f;
#pragma unroll
  for (int p = 0; p < 4; ++p) {
    int a = p * 256 + lane * 4;
    float4 f = *reinterpret_cast<const float4*>(feat + a);
    float4 d = *reinterpret_cast<const float4*>(dfp + a);
    float4 v = *reinterpret_cast<const float4*>(vv + a);
    float4 w = *reinterpret_cast<const float4*>(wcp + a);
    acc += v.x * ftanh(f.x + d.x + cov * w.x);
    acc += v.y * ftanh(f.y + d.y + cov * w.y);
    acc += v.z * ftanh(f.z + d.z + cov * w.z);
    acc += v.w * ftanh(f.w + d.w + cov * w.w);
  }
#pragma unroll
  for (int o = 32; o > 0; o >>= 1) acc += __shfl_xor(acc, o);
  if (lane == 0) e_all[wg] = acc;
}

// K3: per-row softmax (+mask renorm for text) + attn & coverage outputs.
// blocks 0..63 text rows, 64..127 img rows.
__global__ __launch_bounds__(256) void k3_softmax(
    const float* __restrict__ e_all, const float* __restrict__ enc_mask,
    const float* __restrict__ coverage, const float* __restrict__ coverage_img,
    const int* __restrict__ cov_set_p,
    float* __restrict__ out) {
  __shared__ float red[8];
  int bid = blockIdx.x;
  int tid = threadIdx.x;
  float covscale = (float)(*cov_set_p);
  int nk;
  const float *e, *mask, *covin;
  float *attn_out, *cov_out;
  if (bid < 64) {
    nk = 4;
    e = e_all + (size_t)bid * 1024;
    mask = enc_mask + (size_t)bid * 1024;
    covin = coverage + (size_t)bid * 1024;
    attn_out = out + 65536 + (size_t)bid * 1024;
    cov_out  = out + 147456 + (size_t)bid * 1024;
  } else {
    int b = bid - 64;
    nk = 1;
    e = e_all + 65536 + (size_t)b * 256;
    mask = nullptr;
    covin = coverage_img + (size_t)b * 256;
    attn_out = out + 131072 + (size_t)b * 256;
    cov_out  = out + 212992 + (size_t)b * 256;
  }
  float ev[4], mv[4];
  float mx = -1e30f;
  for (int k = 0; k < nk; ++k) {
    int i = k * 256 + tid;
    ev[k] = e[i];
    mv[k] = mask ? mask[i] : 1.f;
    mx = fmaxf(mx, ev[k]);
  }
#pragma unroll
  for (int o = 32; o > 0; o >>= 1) mx = fmaxf(mx, __shfl_xor(mx, o));
  if ((tid & 63) == 0) red[tid >> 6] = mx;
  __syncthreads();
  mx = fmaxf(fmaxf(red[0], red[1]), fmaxf(red[2], red[3]));
  float pv[4];
  float s = 0.f;
  for (int k = 0; k < nk; ++k) {
    pv[k] = __expf(ev[k] - mx) * mv[k];
    s += pv[k];
  }
#pragma unroll
  for (int o = 32; o > 0; o >>= 1) s += __shfl_xor(s, o);
  if ((tid & 63) == 0) red[4 + (tid >> 6)] = s;
  __syncthreads();
  s = red[4] + red[5] + red[6] + red[7];
  float inv = 1.f / s;
  for (int k = 0; k < nk; ++k) {
    int i = k * 256 + tid;
    float at = pv[k] * inv;
    attn_out[i] = at;
    cov_out[i] = covscale * covin[i] + at;  // covscale==0 -> coverage = attn
  }
}

// K4: ctx partials. block = (b, 64-row L chunk); 256 thr * float4 = full A row.
// blocks 0..1023 text (16 chunks/b), 1024..1279 img (4 chunks/b).
__global__ __launch_bounds__(256) void k4_ctx_partial(
    const float* __restrict__ enc_outputs, const float* __restrict__ enc_img_outputs,
    const float* __restrict__ out, float* __restrict__ P4) {
  int bid = blockIdx.x;
  int tid = threadIdx.x;
  const float *src, *attn;
  if (bid < 1024) {
    int b = bid >> 4, c = bid & 15;
    src  = enc_outputs + ((size_t)b * 1024 + c * 64) * 1024;
    attn = out + 65536 + (size_t)b * 1024 + c * 64;
  } else {
    int bi = bid - 1024;
    int b = bi >> 2, c = bi & 3;
    src  = enc_img_outputs + ((size_t)b * 256 + c * 64) * 1024;
    attn = out + 131072 + (size_t)b * 256 + c * 64;
  }
  float4 acc = make_float4(0.f, 0.f, 0.f, 0.f);
#pragma unroll 8
  for (int l = 0; l < 64; ++l) {
    float w = attn[l];  // wave-uniform -> s_load
    float4 r = *reinterpret_cast<const float4*>(src + (size_t)l * 1024 + tid * 4);
    acc.x = fmaf(w, r.x, acc.x);
    acc.y = fmaf(w, r.y, acc.y);
    acc.z = fmaf(w, r.z, acc.z);
    acc.w = fmaf(w, r.w, acc.w);
  }
  *reinterpret_cast<float4*>(P4 + (size_t)bid * 1024 + tid * 4) = acc;
}

// K4b: ctx_t[b][a] = sum_{16 chunks}; ctx_i[b][a] = sum_{4 chunks}
__global__ __launch_bounds__(256) void k4b_reduce(const float* __restrict__ P4,
                                                  float* __restrict__ ctx) {
  int tid = blockIdx.x * 256 + threadIdx.x;  // 0..131071
  int which = tid >> 16;
  int b = (tid >> 10) & 63;
  int a = tid & 1023;
  float s = 0.f;
  if (which == 0) {
    const float* p = P4 + ((size_t)b * 16) * 1024 + a;
#pragma unroll
    for (int c = 0; c < 16; ++c) s += p[(size_t)c * 1024];
    ctx[(size_t)b * 1024 + a] = s;
  } else {
    const float* p = P4 + ((size_t)1024 + b * 4) * 1024 + a;
#pragma unroll
    for (int c = 0; c < 4; ++c) s += p[(size_t)c * 1024];
    ctx[65536 + (size_t)b * 1024 + a] = s;
  }
}

// K5: partials of ctx_t@WA (m=0) and ctx_i@WB (m=1). Same scheme as K1.
__global__ void k5_gemm_ctx(const float* __restrict__ ctx,
                            const float* __restrict__ WA, const float* __restrict__ WB,
                            float* __restrict__ P5) {
  int wid  = blockIdx.x;        // 0..511
  int m    = wid >> 8;          // 0..1
  int at   = (wid >> 2) & 63;
  int kq   = wid & 3;
  int lane = threadIdx.x;
  const float* W = m ? WB : WA;
  const float* csrc = ctx + (size_t)m * 65536 + (size_t)lane * 1024 + kq * 256;
  int a0 = at * 16;
  float acc[16];
#pragma unroll
  for (int t = 0; t < 16; ++t) acc[t] = 0.f;
  for (int kc = 0; kc < 16; ++kc) {
    const float4* dp = reinterpret_cast<const float4*>(csrc + kc * 16);
    float4 d0 = dp[0], d1 = dp[1], d2 = dp[2], d3 = dp[3];
    float dk[16] = {d0.x, d0.y, d0.z, d0.w, d1.x, d1.y, d1.z, d1.w,
                    d2.x, d2.y, d2.z, d2.w, d3.x, d3.y, d3.z, d3.w};
    const float* Wp = W + (size_t)(kq * 256 + kc * 16) * A_DIM + a0;
#pragma unroll
    for (int j = 0; j < 16; ++j) {
#pragma unroll
      for (int t = 0; t < 16; ++t)
        acc[t] = fmaf(dk[j], Wp[(size_t)j * A_DIM + t], acc[t]);
    }
  }
  float* outp = P5 + ((size_t)(m * 4 + kq) * 64 + lane) * A_DIM + a0;
  float4* o4 = reinterpret_cast<float4*>(outp);
  o4[0] = make_float4(acc[0], acc[1], acc[2], acc[3]);
  o4[1] = make_float4(acc[4], acc[5], acc[6], acc[7]);
  o4[2] = make_float4(acc[8], acc[9], acc[10], acc[11]);
  o4[3] = make_float4(acc[12], acc[13], acc[14], acc[15]);
}

// K5b: ctx_mm = v3*tanh(g3+ctx_t@WA)*ctx_t + v4*tanh(g4+ctx_i@WB)*ctx_i
__global__ __launch_bounds__(256) void k5b_final(
    const float* __restrict__ P5, const float* __restrict__ df_all,
    const float* __restrict__ ctx,
    const float* __restrict__ v3, const float* __restrict__ v4,
    float* __restrict__ out) {
  int tid = blockIdx.x * 256 + threadIdx.x;  // 0..65535
  int a = tid & 1023;
  size_t base = tid;
  float sA = P5[base] + P5[base + 65536] + P5[base + 2 * 65536] + P5[base + 3 * 65536];
  float sB = P5[base + 4 * 65536] + P5[base + 5 * 65536] + P5[base + 6 * 65536] +
             P5[base + 7 * 65536];
  float ct = ctx[base];
  float ci = ctx[65536 + base];
  float g3v = df_all[2 * 65536 + base];
  float g4v = df_all[3 * 65536 + base];
  float beta1 = v3[a] * ftanh(g3v + sA);
  float beta2 = v4[a] * ftanh(g4v + sB);
  out[tid] = beta1 * ct + beta2 * ci;
}

extern "C" void kernel_launch(void* const* d_in, const int* in_sizes, int n_in,
                              void* d_out, int out_size, void* d_ws, size_t ws_size,
                              hipStream_t stream) {
  const float* h0            = (const float*)d_in[0];
  const float* h1            = (const float*)d_in[1];
  const float* enc_outputs   = (const float*)d_in[2];
  const float* enc_features  = (const float*)d_in[3];
  const float* enc_mask      = (const float*)d_in[4];
  const float* coverage      = (const float*)d_in[5];
  const float* enc_img_outs  = (const float*)d_in[6];
  const float* enc_img_feats = (const float*)d_in[7];
  // d_in[8] = img_mask (unused by reference)
  const float* coverage_img  = (const float*)d_in[9];
  const int*   cov_set       = (const int*)d_in[10];
  const float* W1 = (const float*)d_in[11];
  const float* b1 = (const float*)d_in[12];
  const float* W2 = (const float*)d_in[13];
  const float* b2 = (const float*)d_in[14];
  const float* W3 = (const float*)d_in[15];
  const float* b3 = (const float*)d_in[16];
  const float* W4 = (const float*)d_in[17];
  const float* b4 = (const float*)d_in[18];
  const float* WA = (const float*)d_in[19];
  const float* WB = (const float*)d_in[20];
  const float* v1 = (const float*)d_in[21];
  const float* v2 = (const float*)d_in[22];
  const float* v3 = (const float*)d_in[23];
  const float* v4 = (const float*)d_in[24];
  const float* wc  = (const float*)d_in[25];
  const float* wci = (const float*)d_in[26];

  float* out = (float*)d_out;
  float* ws  = (float*)d_ws;

  float* PA     = ws;                 // P1 / P4 / P5 (lifetimes disjoint)
  float* df_all = ws + WS_DF_OFF;
  float* e_all  = ws + WS_E_OFF;
  float* ctx    = ws + WS_CTX_OFF;

  k1_gemm_dec<<<dim3(1024), dim3(64), 0, stream>>>(h0, h1, W1, W2, W3, W4, PA);
  k1b_reduce<<<dim3(1024), dim3(256), 0, stream>>>(PA, b1, b2, b3, b4, df_all);
  k2_energy<<<dim3(20480), dim3(256), 0, stream>>>(enc_features, enc_img_feats,
                                                   coverage, coverage_img, df_all,
                                                   v1, v2, wc, wci, cov_set, e_all);
  k3_softmax<<<dim3(128), dim3(256), 0, stream>>>(e_all, enc_mask, coverage,
                                                  coverage_img, cov_set, out);
  k4_ctx_partial<<<dim3(1280), dim3(256), 0, stream>>>(enc_outputs, enc_img_outs,
                                                       out, PA);
  k4b_reduce<<<dim3(512), dim3(256), 0, stream>>>(PA, ctx);
  k5_gemm_ctx<<<dim3(512), dim3(64), 0, stream>>>(ctx, WA, WB, PA);
  k5b_final<<<dim3(256), dim3(256), 0, stream>>>(PA, df_all, ctx, v3, v4, out);
}